// Round 8
// baseline (97.983 us; speedup 1.0000x reference)
//
#include <hip/hip_runtime.h>

#define NB   16
#define INF  512
#define OUTF 512
#define MAXT 80    // sum_b ceil(c_b/16) <= 1024/16 + 15 = 79

typedef __attribute__((ext_vector_type(8))) short bf16x8;
typedef __attribute__((ext_vector_type(4))) float f32x4;

static __device__ __forceinline__ ushort f2bf(float f) {
    unsigned u = __float_as_uint(f);
    u += 0x7FFFu + ((u >> 16) & 1u);   // round-to-nearest-even
    return (ushort)(u >> 16);
}

static __device__ __forceinline__ bf16x8 cvt8(const float* __restrict__ p) {
    float4 v0 = *(const float4*)p;
    float4 v1 = *(const float4*)(p + 4);
    bf16x8 r;
    r[0] = (short)f2bf(v0.x); r[1] = (short)f2bf(v0.y);
    r[2] = (short)f2bf(v0.z); r[3] = (short)f2bf(v0.w);
    r[4] = (short)f2bf(v1.x); r[5] = (short)f2bf(v1.y);
    r[6] = (short)f2bf(v1.z); r[7] = (short)f2bf(v1.w);
    return r;
}

// ---------------- Kernel 1: bucket only (1 block, ~1.5 us) ----------------
// LDS-atomic bucketing (order within a bank irrelevant) + packed worklist:
// tiles[y] = bank<<20 | row0<<8 | mrows  (mrows==0 => dead tile).
// No data conversion pass -- the gemm converts in-register.
__global__ __launch_bounds__(256) void bucket_kernel(
    const int* __restrict__ sel, int* __restrict__ tiles,
    int* __restrict__ lists, int nrows)
{
    __shared__ int cnt[NB];
    int t = threadIdx.x;
    if (t < NB) cnt[t] = 0;
    __syncthreads();
    for (int r = t; r < nrows; r += 256) {
        int b = sel[r];
        int pos = atomicAdd(&cnt[b], 1);
        lists[b * nrows + pos] = r;
    }
    __syncthreads();
    if (t == 0) {
        if (cnt[0] == 0) lists[0] = 0;   // sentinel tiles read lists[0]
        int nt = 0;
        for (int b = 0; b < NB; ++b) {
            int c = cnt[b];
            for (int r0 = 0; r0 < c; r0 += 16) {
                int m = c - r0; if (m > 16) m = 16;
                tiles[nt++] = (b << 20) | (r0 << 8) | m;
            }
        }
        for (; nt < MAXT; ++nt) tiles[nt] = 0;   // mrows=0 sentinel
    }
}

// ---------------- Kernel 2: fp32-direct MFMA gemm ----------------
// grid (8 o-tiles of 64, 80 tiles). 4 waves/block; wave = one 16x16 D tile.
// No LDS, no __syncthreads. fp32 A/B loaded straight from the inputs and
// converted to bf16 fragments in VALU (RNE) right before each MFMA --
// the W conversion pass and its 24 MB ws round-trip are gone.
// unroll 4 + parity-alternating accumulators: VGPR ~<=128, dep depth halved.
__global__ __launch_bounds__(256) void mfma_gemm(
    const float* __restrict__ x, const float* __restrict__ W,
    const float* __restrict__ bias, const int* __restrict__ tiles,
    const int* __restrict__ lists, float* __restrict__ out, int nrows_total)
{
    int tb = tiles[blockIdx.y];
    int mrows = tb & 0xff;
    if (mrows == 0) return;            // sentinel tile
    int bank = tb >> 20;
    int row0 = (tb >> 8) & 0xfff;

    int lane = threadIdx.x & 63;
    int wave = threadIdx.x >> 6;
    int ln = lane & 15;   // A: row m | B/D: out col n
    int q  = lane >> 4;   // k-quad: k offset = q*8

    int o = blockIdx.x * 64 + wave * 16 + ln;
    int rg = lists[bank * nrows_total + row0 + (ln < mrows ? ln : 0)];
    float bv = bias[bank * OUTF + o];

    const float* ap = x + (size_t)rg * INF + q * 8;
    const float* bp = W + ((size_t)bank * OUTF + o) * INF + q * 8;

    f32x4 acc[2];
    acc[0] = (f32x4){0.f, 0.f, 0.f, 0.f};
    acc[1] = (f32x4){0.f, 0.f, 0.f, 0.f};
#pragma unroll 4
    for (int i = 0; i < 16; ++i) {
        bf16x8 a = cvt8(ap + i * 32);
        bf16x8 b = cvt8(bp + i * 32);
        acc[i & 1] = __builtin_amdgcn_mfma_f32_16x16x32_bf16(a, b, acc[i & 1],
                                                             0, 0, 0);
    }

#pragma unroll
    for (int r = 0; r < 4; ++r) {
        int m = q * 4 + r;             // C/D: row = q*4 + reg, col = lane&15
        int rowg = __shfl(rg, m, 16);  // lane m of each 16-group holds row m
        if (m < mrows)
            out[(size_t)rowg * OUTF + o] = acc[0][r] + acc[1][r] + bv;
    }
}

extern "C" void kernel_launch(void* const* d_in, const int* in_sizes, int n_in,
                              void* d_out, int out_size, void* d_ws, size_t ws_size,
                              hipStream_t stream) {
    const float* tensor = (const float*)d_in[0];   // (B,S,K,IN) fp32
    const int*   sel    = (const int*)d_in[1];     // (B,S,K) int32
    const float* weight = (const float*)d_in[2];   // (NB,OUT,IN) fp32
    const float* bias   = (const float*)d_in[3];   // (NB,OUT) fp32
    float* out = (float*)d_out;

    int nrows = in_sizes[1];                       // B*S*K = 1024

    int* tiles = (int*)d_ws;
    int* lists = tiles + MAXT;

    bucket_kernel<<<1, 256, 0, stream>>>(sel, tiles, lists, nrows);
    dim3 grid(OUTF / 64, MAXT, 1);
    mfma_gemm<<<grid, 256, 0, stream>>>(tensor, weight, bias, tiles, lists, out,
                                        nrows);
}

// Round 9
// 87.609 us; speedup vs baseline: 1.1184x; 1.1184x over previous
//
#include <hip/hip_runtime.h>

#define NB   16
#define INF  512
#define OUTF 512
#define MAXT 80    // sum_b ceil(c_b/16) <= 1024/16 + 15 = 79

typedef __attribute__((ext_vector_type(8))) short bf16x8;
typedef __attribute__((ext_vector_type(4))) float f32x4;

static __device__ __forceinline__ ushort f2bf(float f) {
    unsigned u = __float_as_uint(f);
    u += 0x7FFFu + ((u >> 16) & 1u);   // round-to-nearest-even
    return (ushort)(u >> 16);
}

// ws layout (ints): tiles[MAXT] | lists[NB*nrows] ; then bf16 xb | Wb
#define HDR_INTS (MAXT)

// ---------------- Kernel 1: prep ----------------
// block 0: bucket rows by bank via LDS atomics, emit packed tile worklist
//          tiles[y] = bank<<20 | row0<<8 | mrows  (mrows==0 => dead tile)
// blocks 1..: convert W then x to bf16 (grid-stride float4 -> ushort4)
// NOTE (session): this split structure (bulk convert pass + bf16 gemm) is the
// measured optimum. Fused variants (per-block scan R5/R6, in-register cvt R8)
// all regressed 4-10 us: bulk passes amortize at full-chip BW, per-consumer
// work multiplies by the reuse factor.
__global__ __launch_bounds__(256) void prep_kernel(
    const float* __restrict__ x, const int* __restrict__ sel,
    const float* __restrict__ W,
    int* __restrict__ tiles, int* __restrict__ lists,
    ushort* __restrict__ xb, ushort* __restrict__ Wb, int nrows)
{
    int t = threadIdx.x;
    if (blockIdx.x == 0) {
        __shared__ int cnt[NB];
        if (t < NB) cnt[t] = 0;
        __syncthreads();
        for (int r = t; r < nrows; r += 256) {
            int b = sel[r];
            int pos = atomicAdd(&cnt[b], 1);
            lists[b * nrows + pos] = r;
        }
        __syncthreads();
        if (t == 0) {
            if (cnt[0] == 0) lists[0] = 0;   // sentinel tiles read lists[0]
            int nt = 0;
            for (int b = 0; b < NB; ++b) {
                int c = cnt[b];
                for (int r0 = 0; r0 < c; r0 += 16) {
                    int m = c - r0; if (m > 16) m = 16;
                    tiles[nt++] = (b << 20) | (r0 << 8) | m;
                }
            }
            for (; nt < MAXT; ++nt) tiles[nt] = 0;   // mrows=0 sentinel
        }
        return;
    }
    const int nvw = NB * OUTF * INF / 4;
    const int nvx = (nrows * INF) / 4;
    int gid = (blockIdx.x - 1) * 256 + t;
    int stride = (gridDim.x - 1) * 256;
    const float4* Wf = (const float4*)W;
    const float4* xf = (const float4*)x;
    ushort4* Wo = (ushort4*)Wb;
    ushort4* xo = (ushort4*)xb;
    for (int i = gid; i < nvw + nvx; i += stride) {
        if (i < nvw) {
            float4 v = Wf[i];
            ushort4 o;
            o.x = f2bf(v.x); o.y = f2bf(v.y); o.z = f2bf(v.z); o.w = f2bf(v.w);
            Wo[i] = o;
        } else {
            int j = i - nvw;
            float4 v = xf[j];
            ushort4 o;
            o.x = f2bf(v.x); o.y = f2bf(v.y); o.z = f2bf(v.z); o.w = f2bf(v.w);
            xo[j] = o;
        }
    }
}

// ---------------- Kernel 2: barrier-free MFMA gemm ----------------
// grid (8 o-tiles of 64, 80 tiles). 4 waves/block; wave = one 16x16 D tile.
// No LDS, no __syncthreads: per-lane row-index load, store rows via __shfl.
// Two independent MFMA chains halve the accumulator dependency depth.
__global__ __launch_bounds__(256) void mfma_gemm(
    const ushort* __restrict__ xb, const ushort* __restrict__ Wb,
    const float* __restrict__ bias, const int* __restrict__ tiles,
    const int* __restrict__ lists, float* __restrict__ out, int nrows_total)
{
    int tb = tiles[blockIdx.y];
    int mrows = tb & 0xff;
    if (mrows == 0) return;            // sentinel tile
    int bank = tb >> 20;
    int row0 = (tb >> 8) & 0xfff;

    int lane = threadIdx.x & 63;
    int wave = threadIdx.x >> 6;
    int ln = lane & 15;   // A: row m | B/D: out col n
    int q  = lane >> 4;   // k-quad: k offset = q*8

    int o = blockIdx.x * 64 + wave * 16 + ln;
    int rg = lists[bank * nrows_total + row0 + (ln < mrows ? ln : 0)];
    float bv = bias[bank * OUTF + o];

    const ushort* ap = xb + (size_t)rg * INF + q * 8;
    const ushort* bp = Wb + ((size_t)bank * OUTF + o) * INF + q * 8;

    f32x4 acc0 = {0.f, 0.f, 0.f, 0.f};
    f32x4 acc1 = {0.f, 0.f, 0.f, 0.f};
#pragma unroll
    for (int i = 0; i < 8; ++i) {
        bf16x8 a0 = *(const bf16x8*)(ap + (2 * i) * 32);
        bf16x8 b0 = *(const bf16x8*)(bp + (2 * i) * 32);
        bf16x8 a1 = *(const bf16x8*)(ap + (2 * i + 1) * 32);
        bf16x8 b1 = *(const bf16x8*)(bp + (2 * i + 1) * 32);
        acc0 = __builtin_amdgcn_mfma_f32_16x16x32_bf16(a0, b0, acc0, 0, 0, 0);
        acc1 = __builtin_amdgcn_mfma_f32_16x16x32_bf16(a1, b1, acc1, 0, 0, 0);
    }

#pragma unroll
    for (int r = 0; r < 4; ++r) {
        int m = q * 4 + r;             // C/D: row = q*4 + reg, col = lane&15
        int rowg = __shfl(rg, m, 16);  // lane m of each 16-group holds row m
        if (m < mrows)
            out[(size_t)rowg * OUTF + o] = acc0[r] + acc1[r] + bv;
    }
}

extern "C" void kernel_launch(void* const* d_in, const int* in_sizes, int n_in,
                              void* d_out, int out_size, void* d_ws, size_t ws_size,
                              hipStream_t stream) {
    const float* tensor = (const float*)d_in[0];   // (B,S,K,IN) fp32
    const int*   sel    = (const int*)d_in[1];     // (B,S,K) int32
    const float* weight = (const float*)d_in[2];   // (NB,OUT,IN) fp32
    const float* bias   = (const float*)d_in[3];   // (NB,OUT) fp32
    float* out = (float*)d_out;

    int nrows = in_sizes[1];                       // B*S*K = 1024

    int* tiles = (int*)d_ws;
    int* lists = tiles + HDR_INTS;
    size_t int_bytes = (size_t)(HDR_INTS + NB * nrows) * sizeof(int);
    size_t xb_bytes  = (size_t)nrows * INF * sizeof(ushort);
    ushort* xb = (ushort*)((char*)d_ws + int_bytes);
    ushort* Wb = (ushort*)((char*)d_ws + int_bytes + xb_bytes);

    prep_kernel<<<1025, 256, 0, stream>>>(tensor, sel, weight, tiles, lists,
                                          xb, Wb, nrows);
    dim3 grid(OUTF / 64, MAXT, 1);
    mfma_gemm<<<grid, 256, 0, stream>>>(xb, Wb, bias, tiles, lists, out, nrows);
}